// Round 8
// baseline (4333.426 us; speedup 1.0000x reference)
//
#include <hip/hip_runtime.h>

// ---------------------------------------------------------------------------
// LSTM encoder: B=64, S=512, E=256, H=512, gates 4H=2048 (i,f,g,o)
// R8: zero-syncthreads wave-dataflow recurrence.
//  - 64 blocks x 256 thr (4 waves). Block owns units [blk*8, blk*8+8) =
//    W rows [blk*32, +32).  Wave w = batch tile [w*16, +16), BOTH 16-row
//    tiles (2 MFMAs/kk).  W fragments register-resident (128 VGPR).
//  - MFMA operands SWAPPED vs R7: A=W (m=gate-row), B=h^T (n=batch).
//    D lane map (verified R4/R7): n=l&15 (batch), m=(l>>4)*4+reg ->
//    lane koct=l>>4 holds gates 0..3 (reg) of units rt*4+koct ->
//    pointwise is LANE-LOCAL: no Gl LDS, no gate exchange, no syncthreads.
//  - h fragments: per-wave coherent 16B loads (sc0 sc1, L3) with immediate
//    offsets -> no LDS staging at all.  LDS usage: ZERO.
//  - Barrier: per-WAVE flag words (256 flags; plain agent store after
//    vmcnt(0) -- NO atomic RMW serialization), poll = each lane coherent-
//    loads 4 flags (one 16B load covers all 256 across 64 lanes) + __all.
//  R7 measured 3.88us/step latency-bound: 64 serialized counter RMWs +
//  4 syncthreads + LDS stage (2.3e7 bank conflicts) were the overhead.
// Pipeline: P (prep/pack) -> Q (xg precompute, verified) -> R (rec3).
// Fallback (ws too small): naive all-f32 kernel.
// ---------------------------------------------------------------------------

typedef _Float16 half2_t __attribute__((ext_vector_type(2)));
typedef _Float16 half8 __attribute__((ext_vector_type(8)));
typedef float f32x4 __attribute__((ext_vector_type(4)));
typedef short short4_t __attribute__((ext_vector_type(4)));

__device__ __forceinline__ float dot2h(int w, int h, float c) {
#if __has_builtin(__builtin_amdgcn_fdot2)
  return __builtin_amdgcn_fdot2(__builtin_bit_cast(half2_t, w),
                                __builtin_bit_cast(half2_t, h), c, false);
#else
  half2_t a = __builtin_bit_cast(half2_t, w);
  half2_t b = __builtin_bit_cast(half2_t, h);
  return fmaf((float)a[1], (float)b[1], fmaf((float)a[0], (float)b[0], c));
#endif
}

__device__ __forceinline__ float sigm(float x) { return 1.0f / (1.0f + __expf(-x)); }
__device__ __forceinline__ float tanh_(float x) { return 1.0f - 2.0f / (__expf(2.0f * x) + 1.0f); }

// Coherent 16B load (bypass L1/L2, read at L3 coherence point), imm offset.
template <int OFF>
__device__ __forceinline__ int4 ld_c16o(const void* p) {
  int4 v;
  asm volatile("global_load_dwordx4 %0, %1, off offset:%2 sc0 sc1"
               : "=v"(v) : "v"(p), "i"(OFF) : "memory");
  return v;
}

// ---------------------------------------------------------------------------
// P: Wd[(blk*32 + u*4+g)*512 + k] = W_hh[(g*512 + blk*8+u)*512 + k]  (f16)
//    Wip[(k2*512+j)*8+g*2+kk] = W_ih[(g*512+j)*256+2*k2+kk] (k2<128)
//    bsum[j*4+g] = b_ih + b_hh ; H0/H1, cstate, flags[512] zeroed.
// ---------------------------------------------------------------------------
__global__ __launch_bounds__(256) void prep_kernel(
    const float* __restrict__ W_hh, const float* __restrict__ W_ih,
    const float* __restrict__ b_ih, const float* __restrict__ b_hh,
    _Float16* __restrict__ Wd, _Float16* __restrict__ Wip,
    float* __restrict__ bsum, _Float16* __restrict__ Hz,  // H0 (H1 contiguous)
    float* __restrict__ cstate, unsigned* __restrict__ flags) {
  const int S0 = 1048576;            // Wd elements
  const int S1 = S0 + 65536;         // Wip idx (j,k2)
  const int S2 = S1 + 2048;          // bsum
  const int S3 = S2 + 65536;         // H0+H1 halves
  const int S4 = S3 + 32768;         // cstate floats
  const int S5 = S4 + 512;           // flags
  for (int idx = blockIdx.x * blockDim.x + threadIdx.x; idx < S5;
       idx += gridDim.x * blockDim.x) {
    if (idx < S0) {
      int k = idx & 511, row = (idx >> 9) & 31, blk = idx >> 14;
      int u = row >> 2, g = row & 3;
      Wd[idx] = (_Float16)W_hh[(size_t)(g * 512 + blk * 8 + u) * 512 + k];
    } else if (idx < S1) {
      int e = idx - S0;
      int j = e & 511, k2 = e >> 9;  // k2 in [0,128)
#pragma unroll
      for (int g = 0; g < 4; ++g) {
        Wip[(size_t)(k2 * 512 + j) * 8 + g * 2 + 0] =
            (_Float16)W_ih[(size_t)(g * 512 + j) * 256 + 2 * k2 + 0];
        Wip[(size_t)(k2 * 512 + j) * 8 + g * 2 + 1] =
            (_Float16)W_ih[(size_t)(g * 512 + j) * 256 + 2 * k2 + 1];
      }
    } else if (idx < S2) {
      int e = idx - S1;
      int j = e >> 2, g = e & 3;
      bsum[e] = b_ih[g * 512 + j] + b_hh[g * 512 + j];
    } else if (idx < S3) {
      Hz[idx - S2] = (_Float16)0.0f;
    } else if (idx < S4) {
      cstate[idx - S3] = 0.0f;
    } else {
      flags[idx - S4] = 0u;
    }
  }
}

// ---------------------------------------------------------------------------
// Q: x_gates (verified). 8 tokens/block, 512 thr.
// ---------------------------------------------------------------------------
__global__ __launch_bounds__(512, 1) void xg_kernel(
    const int* __restrict__ seq, const float* __restrict__ emb,
    const _Float16* __restrict__ Wip, const float* __restrict__ bsum,
    _Float16* __restrict__ xg, int t0, int Tc) {
  __shared__ int toks[8];
  __shared__ __align__(16) _Float16 el[128 * 16];  // [k2][tok][2]
  const int tid = threadIdx.x;
  const int tau0 = blockIdx.x * 8;

  if (tid < 8) {
    int tau = tau0 + tid;
    int b = tau / Tc, tl = tau - b * Tc;
    toks[tid] = seq[b * 512 + t0 + tl];
  }
  __syncthreads();
  for (int e = tid; e < 2048; e += 512) {
    int i = e >> 8, k = e & 255;
    el[((k >> 1) * 8 + i) * 2 + (k & 1)] = (_Float16)emb[(size_t)toks[i] * 256 + k];
  }
  __syncthreads();

  const int j = tid;
  float4 bs = *(const float4*)&bsum[j * 4];
  float acc[8][4];
#pragma unroll
  for (int i = 0; i < 8; ++i) {
    acc[i][0] = bs.x; acc[i][1] = bs.y; acc[i][2] = bs.z; acc[i][3] = bs.w;
  }
  const _Float16* wp = Wip + (size_t)j * 8;
#pragma unroll 2
  for (int k2 = 0; k2 < 128; ++k2) {
    int4 w = *(const int4*)(wp + (size_t)k2 * 4096);
    int4 e0 = *(const int4*)(el + k2 * 16);
    int4 e1 = *(const int4*)(el + k2 * 16 + 8);
    acc[0][0] = dot2h(w.x, e0.x, acc[0][0]); acc[0][1] = dot2h(w.y, e0.x, acc[0][1]);
    acc[0][2] = dot2h(w.z, e0.x, acc[0][2]); acc[0][3] = dot2h(w.w, e0.x, acc[0][3]);
    acc[1][0] = dot2h(w.x, e0.y, acc[1][0]); acc[1][1] = dot2h(w.y, e0.y, acc[1][1]);
    acc[1][2] = dot2h(w.z, e0.y, acc[1][2]); acc[1][3] = dot2h(w.w, e0.y, acc[1][3]);
    acc[2][0] = dot2h(w.x, e0.z, acc[2][0]); acc[2][1] = dot2h(w.y, e0.z, acc[2][1]);
    acc[2][2] = dot2h(w.z, e0.z, acc[2][2]); acc[2][3] = dot2h(w.w, e0.z, acc[2][3]);
    acc[3][0] = dot2h(w.x, e0.w, acc[3][0]); acc[3][1] = dot2h(w.y, e0.w, acc[3][1]);
    acc[3][2] = dot2h(w.z, e0.w, acc[3][2]); acc[3][3] = dot2h(w.w, e0.w, acc[3][3]);
    acc[4][0] = dot2h(w.x, e1.x, acc[4][0]); acc[4][1] = dot2h(w.y, e1.x, acc[4][1]);
    acc[4][2] = dot2h(w.z, e1.x, acc[4][2]); acc[4][3] = dot2h(w.w, e1.x, acc[4][3]);
    acc[5][0] = dot2h(w.x, e1.y, acc[5][0]); acc[5][1] = dot2h(w.y, e1.y, acc[5][1]);
    acc[5][2] = dot2h(w.z, e1.y, acc[5][2]); acc[5][3] = dot2h(w.w, e1.y, acc[5][3]);
    acc[6][0] = dot2h(w.x, e1.z, acc[6][0]); acc[6][1] = dot2h(w.y, e1.z, acc[6][1]);
    acc[6][2] = dot2h(w.z, e1.z, acc[6][2]); acc[6][3] = dot2h(w.w, e1.z, acc[6][3]);
    acc[7][0] = dot2h(w.x, e1.w, acc[7][0]); acc[7][1] = dot2h(w.y, e1.w, acc[7][1]);
    acc[7][2] = dot2h(w.z, e1.w, acc[7][2]); acc[7][3] = dot2h(w.w, e1.w, acc[7][3]);
  }
#pragma unroll
  for (int i = 0; i < 8; ++i) {
    short4_t sv;
    sv[0] = __builtin_bit_cast(short, (_Float16)acc[i][0]);
    sv[1] = __builtin_bit_cast(short, (_Float16)acc[i][1]);
    sv[2] = __builtin_bit_cast(short, (_Float16)acc[i][2]);
    sv[3] = __builtin_bit_cast(short, (_Float16)acc[i][3]);
    *(short4_t*)(xg + ((size_t)(tau0 + i) * 512 + j) * 4) = sv;
  }
}

// ---------------------------------------------------------------------------
// R: rec3. 64 blocks x 256 thr (4 waves), no LDS, no __syncthreads.
// Wave w: batches [w*16,+16), rows [0,32) of block's W slice.
// Lane l (lm=l&15, koct=l>>4): A-frag rows lm (both 16-row tiles),
// B-frag batch pb=w*16+lm, k=koct*8.. ; D: lane holds gates reg=0..3 of
// units (koct) and (4+koct) for batch pb.
// Per step: 16 coherent h-loads -> 32 MFMA -> lane-local pointwise ->
// packed coherent h-store -> vmcnt(0) -> per-wave flag store -> wave poll.
// ---------------------------------------------------------------------------
__global__ __launch_bounds__(256, 1) void rec3_kernel(
    const _Float16* __restrict__ xg, const _Float16* __restrict__ Wd,
    _Float16* __restrict__ H0, _Float16* __restrict__ H1,
    float* __restrict__ cstate, unsigned* __restrict__ flags,
    float* __restrict__ out, int t0, int Tc) {
  const int blk = blockIdx.x;
  const int tid = threadIdx.x;
  const int l = tid & 63, w = tid >> 6;
  const int lm = l & 15, koct = l >> 4;
  const int pb = w * 16 + lm;          // batch owned
  const int j0 = blk * 8 + koct;       // unit (row-tile 0)
  const int j1 = j0 + 4;               // unit (row-tile 1)

  // W fragments, register-resident (A-operand layout: row=lm, k=koct*8+j)
  half8 Af0[16], Af1[16];
  {
    const _Float16* a0 = Wd + ((size_t)blk * 32 + lm) * 512 + koct * 8;
    const _Float16* a1 = a0 + 16 * 512;
#pragma unroll
    for (int kk = 0; kk < 16; ++kk) {
      Af0[kk] = *(const half8*)(a0 + kk * 32);
      Af1[kk] = *(const half8*)(a1 + kk * 32);
    }
  }

  float c0 = cstate[pb * 512 + j0];
  float c1 = cstate[pb * 512 + j1];

  for (int tl = 0; tl < Tc; ++tl) {
    const int t = t0 + tl;
    const _Float16* Hc = (t & 1) ? H1 : H0;
    _Float16* Hn = (t & 1) ? H0 : H1;

    // ---- h fragments: coherent 16B loads, imm offsets (base + kk*64B)
    const _Float16* hb = Hc + (size_t)pb * 512 + koct * 8;
    int4 bhv[16];
    bhv[0] = ld_c16o<0>(hb);    bhv[1] = ld_c16o<64>(hb);
    bhv[2] = ld_c16o<128>(hb);  bhv[3] = ld_c16o<192>(hb);
    bhv[4] = ld_c16o<256>(hb);  bhv[5] = ld_c16o<320>(hb);
    bhv[6] = ld_c16o<384>(hb);  bhv[7] = ld_c16o<448>(hb);
    bhv[8] = ld_c16o<512>(hb);  bhv[9] = ld_c16o<576>(hb);
    bhv[10] = ld_c16o<640>(hb); bhv[11] = ld_c16o<704>(hb);
    bhv[12] = ld_c16o<768>(hb); bhv[13] = ld_c16o<832>(hb);
    bhv[14] = ld_c16o<896>(hb); bhv[15] = ld_c16o<960>(hb);
    // xg for (pb, j0/j1): plain L2-cached loads
    short4_t xs0 = *(const short4_t*)(xg + ((size_t)(pb * Tc + tl) * 512 + j0) * 4);
    short4_t xs1 = *(const short4_t*)(xg + ((size_t)(pb * Tc + tl) * 512 + j1) * 4);
    asm volatile("s_waitcnt vmcnt(0)" ::: "memory");
    __builtin_amdgcn_sched_barrier(0);

    // ---- 32 MFMA: D = W_tile @ h^T  (A=W: m=row, B=h^T: n=batch)
    f32x4 ac0 = {0.f, 0.f, 0.f, 0.f}, ac1 = {0.f, 0.f, 0.f, 0.f};
#pragma unroll
    for (int kk = 0; kk < 16; ++kk) {
      half8 B = __builtin_bit_cast(half8, bhv[kk]);
      ac0 = __builtin_amdgcn_mfma_f32_16x16x32_f16(Af0[kk], B, ac0, 0, 0, 0);
      ac1 = __builtin_amdgcn_mfma_f32_16x16x32_f16(Af1[kk], B, ac1, 0, 0, 0);
    }

    // ---- lane-local pointwise (acc regs = gates i,f,g,o of (pb, unit))
    float G0 = (float)__builtin_bit_cast(_Float16, (short)xs0[0]) + ac0[0];
    float G1 = (float)__builtin_bit_cast(_Float16, (short)xs0[1]) + ac0[1];
    float G2 = (float)__builtin_bit_cast(_Float16, (short)xs0[2]) + ac0[2];
    float G3 = (float)__builtin_bit_cast(_Float16, (short)xs0[3]) + ac0[3];
    float ig = sigm(G0), fg = sigm(G1), gg = tanh_(G2), og = sigm(G3);
    c0 = fg * c0 + ig * gg;
    float hn0 = og * tanh_(c0);

    G0 = (float)__builtin_bit_cast(_Float16, (short)xs1[0]) + ac1[0];
    G1 = (float)__builtin_bit_cast(_Float16, (short)xs1[1]) + ac1[1];
    G2 = (float)__builtin_bit_cast(_Float16, (short)xs1[2]) + ac1[2];
    G3 = (float)__builtin_bit_cast(_Float16, (short)xs1[3]) + ac1[3];
    float ig1 = sigm(G0), fg1 = sigm(G1), gg1 = tanh_(G2), og1 = sigm(G3);
    c1 = fg1 * c1 + ig1 * gg1;
    float hn1 = og1 * tanh_(c1);

    // ---- packed coherent h stores (pair units across koct^1 lanes)
    unsigned hb0 = (unsigned)__builtin_bit_cast(unsigned short, (_Float16)hn0);
    unsigned hb1 = (unsigned)__builtin_bit_cast(unsigned short, (_Float16)hn1);
    unsigned nb0 = (unsigned)__shfl_xor((int)hb0, 16, 64);
    unsigned nb1 = (unsigned)__shfl_xor((int)hb1, 16, 64);
    if ((koct & 1) == 0) {
      unsigned* bse = (unsigned*)(Hn + (size_t)pb * 512 + blk * 8);
      __hip_atomic_store(bse + (koct >> 1), hb0 | (nb0 << 16),
                         __ATOMIC_RELAXED, __HIP_MEMORY_SCOPE_AGENT);
      __hip_atomic_store(bse + 2 + (koct >> 1), hb1 | (nb1 << 16),
                         __ATOMIC_RELAXED, __HIP_MEMORY_SCOPE_AGENT);
    }
    if (t == 511) {
      out[pb * 512 + j0] = hn0; out[32768 + pb * 512 + j0] = c0;
      out[pb * 512 + j1] = hn1; out[32768 + pb * 512 + j1] = c1;
    }

    // ---- per-wave flag signal + parallel poll (skip after last local step)
    if (tl != Tc - 1) {
      asm volatile("s_waitcnt vmcnt(0)" ::: "memory");  // h stores acked at L3
      if (l == 0)
        __hip_atomic_store(flags + blk * 4 + w, (unsigned)(t + 1),
                           __ATOMIC_RELAXED, __HIP_MEMORY_SCOPE_AGENT);
      const int tgt = t + 1;
      while (true) {
        int4 f = ld_c16o<0>(flags + (l << 2));  // lane l: flags[4l..4l+3]
        asm volatile("s_waitcnt vmcnt(0)" ::: "memory");
        int mn = min(min(f.x, f.y), min(f.z, f.w));
        if (__all(mn >= tgt)) break;
        __builtin_amdgcn_s_sleep(1);
      }
    }
  }
  cstate[pb * 512 + j0] = c0;
  cstate[pb * 512 + j1] = c1;
}

// ---------------------------------------------------------------------------
// Fallback: all-f32 straight from inputs (only if ws_size is tiny).
// ---------------------------------------------------------------------------
__global__ __launch_bounds__(512, 1) void naive_kernel(
    const int* __restrict__ seq, const float* __restrict__ emb,
    const float* __restrict__ W_ih, const float* __restrict__ W_hh,
    const float* __restrict__ b_ih, const float* __restrict__ b_hh,
    float* __restrict__ out) {
  __shared__ float hl[512];
  const int b = blockIdx.x, j = threadIdx.x;
  hl[j] = 0.f;
  float c = 0.f;
  __syncthreads();
  for (int t = 0; t < 512; ++t) {
    int tok = seq[b * 512 + t];
    float A[4];
#pragma unroll
    for (int g = 0; g < 4; ++g) A[g] = b_ih[g * 512 + j] + b_hh[g * 512 + j];
    for (int k = 0; k < 256; ++k) {
      float e = emb[(size_t)tok * 256 + k];
#pragma unroll
      for (int g = 0; g < 4; ++g) A[g] += e * W_ih[(size_t)(g * 512 + j) * 256 + k];
    }
    for (int k = 0; k < 512; ++k) {
      float h = hl[k];
#pragma unroll
      for (int g = 0; g < 4; ++g) A[g] += h * W_hh[(size_t)(g * 512 + j) * 512 + k];
    }
    __syncthreads();
    float ig = sigm(A[0]), fg = sigm(A[1]), gg = tanh_(A[2]), og = sigm(A[3]);
    c = fg * c + ig * gg;
    float hn = og * tanh_(c);
    hl[j] = hn;
    __syncthreads();
    if (t == 511) {
      out[b * 512 + j] = hn;
      out[32768 + b * 512 + j] = c;
    }
  }
}

// ---------------------------------------------------------------------------
extern "C" void kernel_launch(void* const* d_in, const int* in_sizes, int n_in,
                              void* d_out, int out_size, void* d_ws, size_t ws_size,
                              hipStream_t stream) {
  const int* seq = (const int*)d_in[0];
  const float* emb = (const float*)d_in[1];
  const float* W_ih = (const float*)d_in[2];
  const float* W_hh = (const float*)d_in[3];
  const float* b_ih = (const float*)d_in[4];
  const float* b_hh = (const float*)d_in[5];
  float* out = (float*)d_out;

  // workspace layout
  char* w = (char*)d_ws;
  _Float16* Wd = (_Float16*)(w + 0);            // 2,097,152 B
  _Float16* Wip = (_Float16*)(w + 2097152);     // 1,048,576 B
  float* bsum = (float*)(w + 3145728);          //     8,192 B
  _Float16* H0 = (_Float16*)(w + 3153920);      //    65,536 B
  _Float16* H1 = (_Float16*)(w + 3219456);      //    65,536 B
  float* cstate = (float*)(w + 3284992);        //   131,072 B
  unsigned* flags = (unsigned*)(w + 3416064);   //     2,048 B (512 slots)
  _Float16* xgbuf = (_Float16*)(w + 3418112);   // Tc*262,144 B
  const size_t base = 3418112;

  int Tc = 0;
  const int cands[7] = {512, 256, 128, 64, 32, 16, 8};
  for (int ci = 0; ci < 7; ++ci) {
    if (base + (size_t)cands[ci] * 262144 <= ws_size) { Tc = cands[ci]; break; }
  }

  if (Tc == 0) {
    naive_kernel<<<64, 512, 0, stream>>>(seq, emb, W_ih, W_hh, b_ih, b_hh, out);
    return;
  }

  prep_kernel<<<1024, 256, 0, stream>>>(W_hh, W_ih, b_ih, b_hh, Wd, Wip, bsum,
                                        H0, cstate, flags);
  for (int t0 = 0; t0 < 512; t0 += Tc) {
    xg_kernel<<<8 * Tc, 512, 0, stream>>>(seq, emb, Wip, bsum, xgbuf, t0, Tc);
    rec3_kernel<<<64, 256, 0, stream>>>(xgbuf, Wd, H0, H1, cstate, flags, out,
                                        t0, Tc);
  }
}

// Round 9
// 2691.439 us; speedup vs baseline: 1.6101x; 1.6101x over previous
//
#include <hip/hip_runtime.h>

// ---------------------------------------------------------------------------
// LSTM encoder: B=64, S=512, E=256, H=512, gates 4H=2048 (i,f,g,o)
// R9: R8's wave-dataflow compute (verified) + minimal-traffic barrier.
//  - 64 blocks x 256 thr (4 waves). Block owns units [blk*8,+8) = W rows
//    [blk*32,+32); wave w = batch tile [w*16,+16), both 16-row tiles.
//    W register-resident (128 VGPR/lane). MFMA A=W, B=h^T -> lane-local
//    pointwise (D: n=l&15 batch, m=(l>>4)*4+reg = gates). Zero LDS data.
//  - h: coherent 16B loads / packed 4B stores through L3 (sc0 sc1).
//  - R9 barrier fix (R8 regressed 2x from poll traffic: 256 waves x 64
//    lanes x 16B = 256KB/round hammering 16 flag lines): per-wave vmcnt(0)
//    -> syncthreads -> thread0 stores ONE per-block flag (64B-strided) ->
//    ONLY wave 0 polls (lane l loads flag[l], 4B, one RT for all 64) ->
//    syncthreads releases. Poll traffic 16KB/round device-wide.
// Pipeline: P (prep/pack) -> Q (xg precompute, verified) -> R (rec3).
// Fallback (ws too small): naive all-f32 kernel.
// ---------------------------------------------------------------------------

typedef _Float16 half2_t __attribute__((ext_vector_type(2)));
typedef _Float16 half8 __attribute__((ext_vector_type(8)));
typedef float f32x4 __attribute__((ext_vector_type(4)));
typedef short short4_t __attribute__((ext_vector_type(4)));

__device__ __forceinline__ float dot2h(int w, int h, float c) {
#if __has_builtin(__builtin_amdgcn_fdot2)
  return __builtin_amdgcn_fdot2(__builtin_bit_cast(half2_t, w),
                                __builtin_bit_cast(half2_t, h), c, false);
#else
  half2_t a = __builtin_bit_cast(half2_t, w);
  half2_t b = __builtin_bit_cast(half2_t, h);
  return fmaf((float)a[1], (float)b[1], fmaf((float)a[0], (float)b[0], c));
#endif
}

__device__ __forceinline__ float sigm(float x) { return 1.0f / (1.0f + __expf(-x)); }
__device__ __forceinline__ float tanh_(float x) { return 1.0f - 2.0f / (__expf(2.0f * x) + 1.0f); }

// Coherent 16B load (bypass L1/L2, read at L3 coherence point), imm offset.
template <int OFF>
__device__ __forceinline__ int4 ld_c16o(const void* p) {
  int4 v;
  asm volatile("global_load_dwordx4 %0, %1, off offset:%2 sc0 sc1"
               : "=v"(v) : "v"(p), "i"(OFF) : "memory");
  return v;
}

// ---------------------------------------------------------------------------
// P: Wd[(blk*32 + u*4+g)*512 + k] = W_hh[(g*512 + blk*8+u)*512 + k]  (f16)
//    Wip[(k2*512+j)*8+g*2+kk] = W_ih[(g*512+j)*256+2*k2+kk] (k2<128)
//    bsum[j*4+g] = b_ih + b_hh ; H0/H1, cstate, flags[1024] zeroed.
// ---------------------------------------------------------------------------
__global__ __launch_bounds__(256) void prep_kernel(
    const float* __restrict__ W_hh, const float* __restrict__ W_ih,
    const float* __restrict__ b_ih, const float* __restrict__ b_hh,
    _Float16* __restrict__ Wd, _Float16* __restrict__ Wip,
    float* __restrict__ bsum, _Float16* __restrict__ Hz,  // H0 (H1 contiguous)
    float* __restrict__ cstate, unsigned* __restrict__ flags) {
  const int S0 = 1048576;            // Wd elements
  const int S1 = S0 + 65536;         // Wip idx (j,k2)
  const int S2 = S1 + 2048;          // bsum
  const int S3 = S2 + 65536;         // H0+H1 halves
  const int S4 = S3 + 32768;         // cstate floats
  const int S5 = S4 + 1024;          // flags (64 used, 64B-strided)
  for (int idx = blockIdx.x * blockDim.x + threadIdx.x; idx < S5;
       idx += gridDim.x * blockDim.x) {
    if (idx < S0) {
      int k = idx & 511, row = (idx >> 9) & 31, blk = idx >> 14;
      int u = row >> 2, g = row & 3;
      Wd[idx] = (_Float16)W_hh[(size_t)(g * 512 + blk * 8 + u) * 512 + k];
    } else if (idx < S1) {
      int e = idx - S0;
      int j = e & 511, k2 = e >> 9;  // k2 in [0,128)
#pragma unroll
      for (int g = 0; g < 4; ++g) {
        Wip[(size_t)(k2 * 512 + j) * 8 + g * 2 + 0] =
            (_Float16)W_ih[(size_t)(g * 512 + j) * 256 + 2 * k2 + 0];
        Wip[(size_t)(k2 * 512 + j) * 8 + g * 2 + 1] =
            (_Float16)W_ih[(size_t)(g * 512 + j) * 256 + 2 * k2 + 1];
      }
    } else if (idx < S2) {
      int e = idx - S1;
      int j = e >> 2, g = e & 3;
      bsum[e] = b_ih[g * 512 + j] + b_hh[g * 512 + j];
    } else if (idx < S3) {
      Hz[idx - S2] = (_Float16)0.0f;
    } else if (idx < S4) {
      cstate[idx - S3] = 0.0f;
    } else {
      flags[idx - S4] = 0u;
    }
  }
}

// ---------------------------------------------------------------------------
// Q: x_gates (verified). 8 tokens/block, 512 thr.
// ---------------------------------------------------------------------------
__global__ __launch_bounds__(512, 1) void xg_kernel(
    const int* __restrict__ seq, const float* __restrict__ emb,
    const _Float16* __restrict__ Wip, const float* __restrict__ bsum,
    _Float16* __restrict__ xg, int t0, int Tc) {
  __shared__ int toks[8];
  __shared__ __align__(16) _Float16 el[128 * 16];  // [k2][tok][2]
  const int tid = threadIdx.x;
  const int tau0 = blockIdx.x * 8;

  if (tid < 8) {
    int tau = tau0 + tid;
    int b = tau / Tc, tl = tau - b * Tc;
    toks[tid] = seq[b * 512 + t0 + tl];
  }
  __syncthreads();
  for (int e = tid; e < 2048; e += 512) {
    int i = e >> 8, k = e & 255;
    el[((k >> 1) * 8 + i) * 2 + (k & 1)] = (_Float16)emb[(size_t)toks[i] * 256 + k];
  }
  __syncthreads();

  const int j = tid;
  float4 bs = *(const float4*)&bsum[j * 4];
  float acc[8][4];
#pragma unroll
  for (int i = 0; i < 8; ++i) {
    acc[i][0] = bs.x; acc[i][1] = bs.y; acc[i][2] = bs.z; acc[i][3] = bs.w;
  }
  const _Float16* wp = Wip + (size_t)j * 8;
#pragma unroll 2
  for (int k2 = 0; k2 < 128; ++k2) {
    int4 w = *(const int4*)(wp + (size_t)k2 * 4096);
    int4 e0 = *(const int4*)(el + k2 * 16);
    int4 e1 = *(const int4*)(el + k2 * 16 + 8);
    acc[0][0] = dot2h(w.x, e0.x, acc[0][0]); acc[0][1] = dot2h(w.y, e0.x, acc[0][1]);
    acc[0][2] = dot2h(w.z, e0.x, acc[0][2]); acc[0][3] = dot2h(w.w, e0.x, acc[0][3]);
    acc[1][0] = dot2h(w.x, e0.y, acc[1][0]); acc[1][1] = dot2h(w.y, e0.y, acc[1][1]);
    acc[1][2] = dot2h(w.z, e0.y, acc[1][2]); acc[1][3] = dot2h(w.w, e0.y, acc[1][3]);
    acc[2][0] = dot2h(w.x, e0.z, acc[2][0]); acc[2][1] = dot2h(w.y, e0.z, acc[2][1]);
    acc[2][2] = dot2h(w.z, e0.z, acc[2][2]); acc[2][3] = dot2h(w.w, e0.z, acc[2][3]);
    acc[3][0] = dot2h(w.x, e0.w, acc[3][0]); acc[3][1] = dot2h(w.y, e0.w, acc[3][1]);
    acc[3][2] = dot2h(w.z, e0.w, acc[3][2]); acc[3][3] = dot2h(w.w, e0.w, acc[3][3]);
    acc[4][0] = dot2h(w.x, e1.x, acc[4][0]); acc[4][1] = dot2h(w.y, e1.x, acc[4][1]);
    acc[4][2] = dot2h(w.z, e1.x, acc[4][2]); acc[4][3] = dot2h(w.w, e1.x, acc[4][3]);
    acc[5][0] = dot2h(w.x, e1.y, acc[5][0]); acc[5][1] = dot2h(w.y, e1.y, acc[5][1]);
    acc[5][2] = dot2h(w.z, e1.y, acc[5][2]); acc[5][3] = dot2h(w.w, e1.y, acc[5][3]);
    acc[6][0] = dot2h(w.x, e1.z, acc[6][0]); acc[6][1] = dot2h(w.y, e1.z, acc[6][1]);
    acc[6][2] = dot2h(w.z, e1.z, acc[6][2]); acc[6][3] = dot2h(w.w, e1.z, acc[6][3]);
    acc[7][0] = dot2h(w.x, e1.w, acc[7][0]); acc[7][1] = dot2h(w.y, e1.w, acc[7][1]);
    acc[7][2] = dot2h(w.z, e1.w, acc[7][2]); acc[7][3] = dot2h(w.w, e1.w, acc[7][3]);
  }
#pragma unroll
  for (int i = 0; i < 8; ++i) {
    short4_t sv;
    sv[0] = __builtin_bit_cast(short, (_Float16)acc[i][0]);
    sv[1] = __builtin_bit_cast(short, (_Float16)acc[i][1]);
    sv[2] = __builtin_bit_cast(short, (_Float16)acc[i][2]);
    sv[3] = __builtin_bit_cast(short, (_Float16)acc[i][3]);
    *(short4_t*)(xg + ((size_t)(tau0 + i) * 512 + j) * 4) = sv;
  }
}

// ---------------------------------------------------------------------------
// R: rec3. 64 blocks x 256 thr (4 waves), zero LDS data traffic.
// Wave w: batches [w*16,+16), rows [0,32) of block's W slice.
// Lane l (lm=l&15, koct=l>>4): A rows lm (both row tiles), B batch
// pb=w*16+lm; D: lane holds gates reg 0..3 of units koct / 4+koct.
// Per step: 16 coherent h-loads -> 32 MFMA -> lane-local pointwise ->
// packed coherent h-store -> vmcnt(0) -> syncthreads -> thread0 block-flag
// -> wave0 parallel poll (lane l reads flag[l]) -> syncthreads.
// ---------------------------------------------------------------------------
__global__ __launch_bounds__(256, 1) void rec3_kernel(
    const _Float16* __restrict__ xg, const _Float16* __restrict__ Wd,
    _Float16* __restrict__ H0, _Float16* __restrict__ H1,
    float* __restrict__ cstate, unsigned* __restrict__ flags,
    float* __restrict__ out, int t0, int Tc) {
  const int blk = blockIdx.x;
  const int tid = threadIdx.x;
  const int l = tid & 63, w = tid >> 6;
  const int lm = l & 15, koct = l >> 4;
  const int pb = w * 16 + lm;          // batch owned
  const int j0 = blk * 8 + koct;       // unit (row-tile 0)
  const int j1 = j0 + 4;               // unit (row-tile 1)

  // W fragments, register-resident (A-operand layout: row=lm, k=koct*8+j)
  half8 Af0[16], Af1[16];
  {
    const _Float16* a0 = Wd + ((size_t)blk * 32 + lm) * 512 + koct * 8;
    const _Float16* a1 = a0 + 16 * 512;
#pragma unroll
    for (int kk = 0; kk < 16; ++kk) {
      Af0[kk] = *(const half8*)(a0 + kk * 32);
      Af1[kk] = *(const half8*)(a1 + kk * 32);
    }
  }

  float c0 = cstate[pb * 512 + j0];
  float c1 = cstate[pb * 512 + j1];

  for (int tl = 0; tl < Tc; ++tl) {
    const int t = t0 + tl;
    const _Float16* Hc = (t & 1) ? H1 : H0;
    _Float16* Hn = (t & 1) ? H0 : H1;

    // ---- h fragments: coherent 16B loads, imm offsets (base + kk*64B)
    const _Float16* hb = Hc + (size_t)pb * 512 + koct * 8;
    int4 bhv[16];
    bhv[0] = ld_c16o<0>(hb);    bhv[1] = ld_c16o<64>(hb);
    bhv[2] = ld_c16o<128>(hb);  bhv[3] = ld_c16o<192>(hb);
    bhv[4] = ld_c16o<256>(hb);  bhv[5] = ld_c16o<320>(hb);
    bhv[6] = ld_c16o<384>(hb);  bhv[7] = ld_c16o<448>(hb);
    bhv[8] = ld_c16o<512>(hb);  bhv[9] = ld_c16o<576>(hb);
    bhv[10] = ld_c16o<640>(hb); bhv[11] = ld_c16o<704>(hb);
    bhv[12] = ld_c16o<768>(hb); bhv[13] = ld_c16o<832>(hb);
    bhv[14] = ld_c16o<896>(hb); bhv[15] = ld_c16o<960>(hb);
    // xg for (pb, j0/j1): plain L2-cached loads
    short4_t xs0 = *(const short4_t*)(xg + ((size_t)(pb * Tc + tl) * 512 + j0) * 4);
    short4_t xs1 = *(const short4_t*)(xg + ((size_t)(pb * Tc + tl) * 512 + j1) * 4);
    asm volatile("s_waitcnt vmcnt(0)" ::: "memory");
    __builtin_amdgcn_sched_barrier(0);

    // ---- 32 MFMA: D = W_tile @ h^T  (A=W: m=row, B=h^T: n=batch)
    f32x4 ac0 = {0.f, 0.f, 0.f, 0.f}, ac1 = {0.f, 0.f, 0.f, 0.f};
#pragma unroll
    for (int kk = 0; kk < 16; ++kk) {
      half8 B = __builtin_bit_cast(half8, bhv[kk]);
      ac0 = __builtin_amdgcn_mfma_f32_16x16x32_f16(Af0[kk], B, ac0, 0, 0, 0);
      ac1 = __builtin_amdgcn_mfma_f32_16x16x32_f16(Af1[kk], B, ac1, 0, 0, 0);
    }

    // ---- lane-local pointwise (acc regs = gates i,f,g,o of (pb, unit))
    float G0 = (float)__builtin_bit_cast(_Float16, (short)xs0[0]) + ac0[0];
    float G1 = (float)__builtin_bit_cast(_Float16, (short)xs0[1]) + ac0[1];
    float G2 = (float)__builtin_bit_cast(_Float16, (short)xs0[2]) + ac0[2];
    float G3 = (float)__builtin_bit_cast(_Float16, (short)xs0[3]) + ac0[3];
    float ig = sigm(G0), fg = sigm(G1), gg = tanh_(G2), og = sigm(G3);
    c0 = fg * c0 + ig * gg;
    float hn0 = og * tanh_(c0);

    G0 = (float)__builtin_bit_cast(_Float16, (short)xs1[0]) + ac1[0];
    G1 = (float)__builtin_bit_cast(_Float16, (short)xs1[1]) + ac1[1];
    G2 = (float)__builtin_bit_cast(_Float16, (short)xs1[2]) + ac1[2];
    G3 = (float)__builtin_bit_cast(_Float16, (short)xs1[3]) + ac1[3];
    float ig1 = sigm(G0), fg1 = sigm(G1), gg1 = tanh_(G2), og1 = sigm(G3);
    c1 = fg1 * c1 + ig1 * gg1;
    float hn1 = og1 * tanh_(c1);

    // ---- packed coherent h stores (pair units across koct^1 lanes)
    unsigned hb0 = (unsigned)__builtin_bit_cast(unsigned short, (_Float16)hn0);
    unsigned hb1 = (unsigned)__builtin_bit_cast(unsigned short, (_Float16)hn1);
    unsigned nb0 = (unsigned)__shfl_xor((int)hb0, 16, 64);
    unsigned nb1 = (unsigned)__shfl_xor((int)hb1, 16, 64);
    if ((koct & 1) == 0) {
      unsigned* bse = (unsigned*)(Hn + (size_t)pb * 512 + blk * 8);
      __hip_atomic_store(bse + (koct >> 1), hb0 | (nb0 << 16),
                         __ATOMIC_RELAXED, __HIP_MEMORY_SCOPE_AGENT);
      __hip_atomic_store(bse + 2 + (koct >> 1), hb1 | (nb1 << 16),
                         __ATOMIC_RELAXED, __HIP_MEMORY_SCOPE_AGENT);
    }
    if (t == 511) {
      out[pb * 512 + j0] = hn0; out[32768 + pb * 512 + j0] = c0;
      out[pb * 512 + j1] = hn1; out[32768 + pb * 512 + j1] = c1;
    }

    // ---- barrier: block flag + single-wave parallel poll
    if (tl != Tc - 1) {
      asm volatile("s_waitcnt vmcnt(0)" ::: "memory");  // this wave's stores acked
      __syncthreads();                                   // => all waves' acked
      if (tid == 0)
        __hip_atomic_store(flags + blk * 16, (unsigned)(t + 1),
                           __ATOMIC_RELAXED, __HIP_MEMORY_SCOPE_AGENT);
      if (w == 0) {
        const unsigned tgt = (unsigned)(t + 1);
        while (true) {
          unsigned f;
          asm volatile("global_load_dword %0, %1, off sc0 sc1"
                       : "=v"(f) : "v"(flags + l * 16) : "memory");
          asm volatile("s_waitcnt vmcnt(0)" ::: "memory");
          if (__all((int)(f >= tgt))) break;
          __builtin_amdgcn_s_sleep(1);
        }
      }
      __syncthreads();
    }
  }
  cstate[pb * 512 + j0] = c0;
  cstate[pb * 512 + j1] = c1;
}

// ---------------------------------------------------------------------------
// Fallback: all-f32 straight from inputs (only if ws_size is tiny).
// ---------------------------------------------------------------------------
__global__ __launch_bounds__(512, 1) void naive_kernel(
    const int* __restrict__ seq, const float* __restrict__ emb,
    const float* __restrict__ W_ih, const float* __restrict__ W_hh,
    const float* __restrict__ b_ih, const float* __restrict__ b_hh,
    float* __restrict__ out) {
  __shared__ float hl[512];
  const int b = blockIdx.x, j = threadIdx.x;
  hl[j] = 0.f;
  float c = 0.f;
  __syncthreads();
  for (int t = 0; t < 512; ++t) {
    int tok = seq[b * 512 + t];
    float A[4];
#pragma unroll
    for (int g = 0; g < 4; ++g) A[g] = b_ih[g * 512 + j] + b_hh[g * 512 + j];
    for (int k = 0; k < 256; ++k) {
      float e = emb[(size_t)tok * 256 + k];
#pragma unroll
      for (int g = 0; g < 4; ++g) A[g] += e * W_ih[(size_t)(g * 512 + j) * 256 + k];
    }
    for (int k = 0; k < 512; ++k) {
      float h = hl[k];
#pragma unroll
      for (int g = 0; g < 4; ++g) A[g] += h * W_hh[(size_t)(g * 512 + j) * 512 + k];
    }
    __syncthreads();
    float ig = sigm(A[0]), fg = sigm(A[1]), gg = tanh_(A[2]), og = sigm(A[3]);
    c = fg * c + ig * gg;
    float hn = og * tanh_(c);
    hl[j] = hn;
    __syncthreads();
    if (t == 511) {
      out[b * 512 + j] = hn;
      out[32768 + b * 512 + j] = c;
    }
  }
}

// ---------------------------------------------------------------------------
extern "C" void kernel_launch(void* const* d_in, const int* in_sizes, int n_in,
                              void* d_out, int out_size, void* d_ws, size_t ws_size,
                              hipStream_t stream) {
  const int* seq = (const int*)d_in[0];
  const float* emb = (const float*)d_in[1];
  const float* W_ih = (const float*)d_in[2];
  const float* W_hh = (const float*)d_in[3];
  const float* b_ih = (const float*)d_in[4];
  const float* b_hh = (const float*)d_in[5];
  float* out = (float*)d_out;

  // workspace layout
  char* w = (char*)d_ws;
  _Float16* Wd = (_Float16*)(w + 0);            // 2,097,152 B
  _Float16* Wip = (_Float16*)(w + 2097152);     // 1,048,576 B
  float* bsum = (float*)(w + 3145728);          //     8,192 B
  _Float16* H0 = (_Float16*)(w + 3153920);      //    65,536 B
  _Float16* H1 = (_Float16*)(w + 3219456);      //    65,536 B
  float* cstate = (float*)(w + 3284992);        //   131,072 B
  unsigned* flags = (unsigned*)(w + 3416064);   //     4,096 B (64 used, 64B stride)
  _Float16* xgbuf = (_Float16*)(w + 3420160);   // Tc*262,144 B
  const size_t base = 3420160;

  int Tc = 0;
  const int cands[7] = {512, 256, 128, 64, 32, 16, 8};
  for (int ci = 0; ci < 7; ++ci) {
    if (base + (size_t)cands[ci] * 262144 <= ws_size) { Tc = cands[ci]; break; }
  }

  if (Tc == 0) {
    naive_kernel<<<64, 512, 0, stream>>>(seq, emb, W_ih, W_hh, b_ih, b_hh, out);
    return;
  }

  prep_kernel<<<1024, 256, 0, stream>>>(W_hh, W_ih, b_ih, b_hh, Wd, Wip, bsum,
                                        H0, cstate, flags);
  for (int t0 = 0; t0 < 512; t0 += Tc) {
    xg_kernel<<<8 * Tc, 512, 0, stream>>>(seq, emb, Wip, bsum, xgbuf, t0, Tc);
    rec3_kernel<<<64, 256, 0, stream>>>(xgbuf, Wd, H0, H1, cstate, flags, out,
                                        t0, Tc);
  }
}